// Round 8
// baseline (207.331 us; speedup 1.0000x reference)
//
#include <hip/hip_runtime.h>
#include <hip/hip_bf16.h>
#include <math.h>

#define BB 8
#define LL 4096
#define DD 512
#define CH 16            // positions per pooling chunk (one wave handles CH rows x 256 cols)

typedef __attribute__((ext_vector_type(8))) short bfx8;
typedef __attribute__((ext_vector_type(8))) unsigned short usx8;
typedef __attribute__((ext_vector_type(4))) float fx4;

static __device__ __forceinline__ unsigned short bf_hi(float x) {
    __hip_bfloat16 h = __float2bfloat16(x);
    return *reinterpret_cast<unsigned short*>(&h);
}
static __device__ __forceinline__ float bf_f(unsigned short u) {
    __hip_bfloat16 h = *reinterpret_cast<__hip_bfloat16*>(&u);
    return __bfloat162float(h);
}
static __device__ __forceinline__ void glds16(const void* g, void* l) {
    __builtin_amdgcn_global_load_lds(
        (const __attribute__((address_space(1))) unsigned int*)g,
        (__attribute__((address_space(3))) unsigned int*)l, 16, 0, 0);
}

// ---------------------------------------------------------------------------
// K0: LDS-transpose split of W1 (fp32 [K][N]) -> wt_hi/wt_lo bf16 [N][K].
// 64 blocks x 256 thr; 64x64 tile: coalesced float4 reads, padded LDS,
// packed 16B bf16 writes. Also zeroes logits (exactly 2 elems/thread).
// ---------------------------------------------------------------------------
__global__ __launch_bounds__(256)
void k_split(const float* __restrict__ W1, unsigned short* __restrict__ wt_hi,
             unsigned short* __restrict__ wt_lo, float* __restrict__ logits) {
    __shared__ float tile[64][65];
    const int tid = threadIdx.x;
    const int kt  = blockIdx.x >> 3;     // k-tile 0..7
    const int nt  = blockIdx.x & 7;      // n-tile 0..7
#pragma unroll
    for (int i = 0; i < 4; i++) {
        int r  = (tid >> 4) + i * 16;
        int c4 = tid & 15;
        float4 v = *reinterpret_cast<const float4*>(
            &W1[(size_t)(kt * 64 + r) * DD + nt * 64 + c4 * 4]);
        tile[r][c4 * 4 + 0] = v.x; tile[r][c4 * 4 + 1] = v.y;
        tile[r][c4 * 4 + 2] = v.z; tile[r][c4 * 4 + 3] = v.w;
    }
    // zero logits: 16384 threads total, 32768 logits
    int g = blockIdx.x * 256 + tid;
    logits[g] = 0.f; logits[g + 16384] = 0.f;
    __syncthreads();
    const int n  = tid >> 2;             // 0..63 (output row within n-tile)
    const int kq = tid & 3;              // 16-k quarter
    usx8 h8[2], l8[2];
#pragma unroll
    for (int q = 0; q < 2; q++)
#pragma unroll
        for (int e = 0; e < 8; e++) {
            float x = tile[kq * 16 + q * 8 + e][n];
            unsigned short hi = bf_hi(x);
            h8[q][e] = (short)hi;
            l8[q][e] = (short)bf_hi(x - bf_f(hi));
        }
    size_t off = (size_t)(nt * 64 + n) * DD + kt * 64 + kq * 16;
    *reinterpret_cast<usx8*>(&wt_hi[off])     = h8[0];
    *reinterpret_cast<usx8*>(&wt_hi[off + 8]) = h8[1];
    *reinterpret_cast<usx8*>(&wt_lo[off])     = l8[0];
    *reinterpret_cast<usx8*>(&wt_lo[off + 8]) = l8[1];
}

// ---------------------------------------------------------------------------
// K1: split-bf16 MFMA GEMM + fused GELU + W2 GEMV -> logits partials
// (unchanged from round 6: 128x128 tile, BK=64, 8 waves, atomicAdd epilogue)
// ---------------------------------------------------------------------------
__global__ __launch_bounds__(512, 4)
void k_mfma(const float* __restrict__ hidden,
            const unsigned short* __restrict__ wt_hi,
            const unsigned short* __restrict__ wt_lo,
            const float* __restrict__ b1, const float* __restrict__ W2,
            float* __restrict__ logits) {
    __shared__ __align__(16) char lds[65536];   // A_hi A_lo B_hi B_lo, 16KB each
    const int tid  = threadIdx.x;
    const int wave = tid >> 6;
    const int lane = tid & 63;
    const int grp  = lane >> 4;
    const int lid  = lane & 15;
    const int wr   = wave >> 2;
    const int wc   = wave & 3;

    int wg = (blockIdx.x & 7) * 128 + (blockIdx.x >> 3);
    const int colTile = wg & 3;
    const int rowTile = wg >> 2;
    const int rowBase = rowTile * 128;
    const int colBase = colTile * 128;

    fx4 acc[4][2];
#pragma unroll
    for (int m = 0; m < 4; m++)
#pragma unroll
        for (int n = 0; n < 2; n++) acc[m][n] = {0.f, 0.f, 0.f, 0.f};

    const int arow = tid >> 2;
    const int aq   = tid & 3;
    const float* aSrc = hidden + (size_t)(rowBase + arow) * DD + aq * 16;

    const unsigned short* bsrc[4];
    char* bdst[4];
#pragma unroll
    for (int i = 0; i < 4; i++) {
        int gi = wave * 4 + i;
        int plane = gi >> 4;
        int pi = gi & 15;
        int col = pi * 8 + (lane >> 3);
        int chunk = (lane & 7) ^ (lane >> 3);
        const unsigned short* srcp = plane ? wt_lo : wt_hi;
        bsrc[i] = srcp + (size_t)(colBase + col) * DD + chunk * 8;
        bdst[i] = lds + 32768 + plane * 16384 + pi * 1024;
    }

    float4 av[4];
#pragma unroll
    for (int j = 0; j < 4; j++) av[j] = *reinterpret_cast<const float4*>(aSrc + j * 4);

    for (int kt = 0; kt < 8; kt++) {
        __syncthreads();
#pragma unroll
        for (int j = 0; j < 2; j++) {
            usx8 hi8, lo8;
            float xv[8] = {av[2*j].x, av[2*j].y, av[2*j].z, av[2*j].w,
                           av[2*j+1].x, av[2*j+1].y, av[2*j+1].z, av[2*j+1].w};
#pragma unroll
            for (int e = 0; e < 8; e++) {
                unsigned short h = bf_hi(xv[e]);
                hi8[e] = (short)h;
                lo8[e] = (short)bf_hi(xv[e] - bf_f(h));
            }
            int aoff = arow * 128 + ((aq * 32 + j * 16) ^ ((arow & 7) << 4));
            *reinterpret_cast<usx8*>(lds + aoff)         = hi8;
            *reinterpret_cast<usx8*>(lds + 16384 + aoff) = lo8;
        }
#pragma unroll
        for (int i = 0; i < 4; i++) glds16(bsrc[i] + kt * 64, bdst[i]);

        __syncthreads();

        if (kt < 7) {
#pragma unroll
            for (int j = 0; j < 4; j++)
                av[j] = *reinterpret_cast<const float4*>(aSrc + (kt + 1) * 64 + j * 4);
        }

#pragma unroll
        for (int ks = 0; ks < 2; ks++) {
            const int kb = ks * 64 + grp * 16;
            const int sw = kb ^ ((lid & 7) << 4);
            bfx8 ah[4], bh[2], bl[2], al[4];
#pragma unroll
            for (int m = 0; m < 4; m++) {
                int off = (wr * 64 + m * 16 + lid) * 128 + sw;
                ah[m] = *reinterpret_cast<const bfx8*>(lds + off);
            }
#pragma unroll
            for (int n = 0; n < 2; n++) {
                int off = (wc * 32 + n * 16 + lid) * 128 + sw;
                bh[n] = *reinterpret_cast<const bfx8*>(lds + 32768 + off);
                bl[n] = *reinterpret_cast<const bfx8*>(lds + 49152 + off);
            }
            __builtin_amdgcn_s_setprio(1);
#pragma unroll
            for (int m = 0; m < 4; m++)
#pragma unroll
                for (int n = 0; n < 2; n++)
                    acc[m][n] = __builtin_amdgcn_mfma_f32_16x16x32_bf16(
                        ah[m], bh[n], acc[m][n], 0, 0, 0);
#pragma unroll
            for (int m = 0; m < 4; m++)
#pragma unroll
                for (int n = 0; n < 2; n++)
                    acc[m][n] = __builtin_amdgcn_mfma_f32_16x16x32_bf16(
                        ah[m], bl[n], acc[m][n], 0, 0, 0);
#pragma unroll
            for (int m = 0; m < 4; m++) {
                int off = (wr * 64 + m * 16 + lid) * 128 + sw;
                al[m] = *reinterpret_cast<const bfx8*>(lds + 16384 + off);
            }
#pragma unroll
            for (int m = 0; m < 4; m++)
#pragma unroll
                for (int n = 0; n < 2; n++)
                    acc[m][n] = __builtin_amdgcn_mfma_f32_16x16x32_bf16(
                        al[m], bh[n], acc[m][n], 0, 0, 0);
            __builtin_amdgcn_s_setprio(0);
        }
    }

    float w2v[2], b1v[2];
#pragma unroll
    for (int n = 0; n < 2; n++) {
        int c = colBase + wc * 32 + n * 16 + lid;
        w2v[n] = W2[c]; b1v[n] = b1[c];
    }
    __syncthreads();
    float* parts = reinterpret_cast<float*>(lds);   // [128][4]
#pragma unroll
    for (int m = 0; m < 4; m++)
#pragma unroll
        for (int reg = 0; reg < 4; reg++) {
            float p = 0.f;
#pragma unroll
            for (int n = 0; n < 2; n++) {
                float v = acc[m][n][reg] + b1v[n];
                float g = 0.5f * v * (1.0f + erff(v * 0.70710678118654752f));
                p += g * w2v[n];
            }
            p += __shfl_xor(p, 1, 64);
            p += __shfl_xor(p, 2, 64);
            p += __shfl_xor(p, 4, 64);
            p += __shfl_xor(p, 8, 64);
            if (lid == 0)
                parts[(wr * 64 + m * 16 + grp * 4 + reg) * 4 + wc] = p;
        }
    __syncthreads();
    if (tid < 128) {
        float4 v = *reinterpret_cast<const float4*>(parts + tid * 4);
        atomicAdd(&logits[rowBase + tid], v.x + v.y + v.z + v.w);
    }
}

// ---------------------------------------------------------------------------
// K2: sigmoid/mask/forced-last (+b2), block scan of hard -> masked_probs,
// scalars, bpos, segid.
// ---------------------------------------------------------------------------
__global__ __launch_bounds__(1024)
void k_bound(const float* __restrict__ logits, const float* __restrict__ lengths,
             const float* __restrict__ b2, float* __restrict__ out, int S,
             int* __restrict__ nseg, int* __restrict__ bpos,
             int* __restrict__ segid) {
    const int b   = blockIdx.x;
    const int tid = threadIdx.x;          // 1024 threads, 4 t each
    const float alenf = lengths[b] * (float)LL;
    const int alen = (int)alenf;
    const float b2v = b2[0];
    int last = alen - 1;
    if (last < 0) last = 0;
    if (last > LL - 1) last = LL - 1;

    float* out_mp = out + (size_t)BB * S * DD;

    float4 lg4 = *reinterpret_cast<const float4*>(&logits[b * LL + tid * 4]);
    const float* lgp = reinterpret_cast<const float*>(&lg4);
    int h[4];
    float4 mp_pack;
    float* mpp = reinterpret_cast<float*>(&mp_pack);
#pragma unroll
    for (int i = 0; i < 4; i++) {
        int t = tid * 4 + i;
        float prob = 1.0f / (1.0f + expf(-(lgp[i] + b2v)));
        bool valid = t < alen;
        mpp[i] = valid ? prob : 0.0f;
        int hd = (prob > 0.5f && valid) ? 1 : 0;
        if (t == last) hd = 1;
        h[i] = hd;
    }
    *reinterpret_cast<float4*>(&out_mp[b * LL + tid * 4]) = mp_pack;

    int s4 = h[0] + h[1] + h[2] + h[3];
    const int lane = tid & 63;
    const int wave = tid >> 6;            // 0..15
    int incl = s4;
#pragma unroll
    for (int off = 1; off < 64; off <<= 1) {
        int v = __shfl_up(incl, off, 64);
        if (lane >= off) incl += v;
    }
    __shared__ int wsum[16];
    __shared__ int woff[17];
    if (lane == 63) wsum[wave] = incl;
    __syncthreads();
    if (tid == 0) {
        int r = 0;
        for (int w = 0; w < 16; w++) { woff[w] = r; r += wsum[w]; }
        woff[16] = r;
    }
    __syncthreads();
    int ex = woff[wave] + incl - s4;
    int4 sg_pack;
    int* sgp = reinterpret_cast<int*>(&sg_pack);
#pragma unroll
    for (int i = 0; i < 4; i++) {
        int t = tid * 4 + i;
        sgp[i] = ex;
        if (h[i]) { bpos[b * LL + ex] = t; ex++; }
    }
    *reinterpret_cast<int4*>(&segid[b * LL + tid * 4]) = sg_pack;

    if (tid == 0) {
        int total = woff[16];
        nseg[b] = total;
        float* out_sl = out + (size_t)BB * S * DD + (size_t)BB * LL;
        float* out_nb = out_sl + BB;
        out_nb[b] = (float)total;
        int denom = (S > 1) ? S : 1;
        out_sl[b] = (float)total / (float)denom;
    }
}

// ---------------------------------------------------------------------------
// K3: chunked segmented mean-pool, v3: one wave per (chunk of CH rows,
// 256-col half). 8192 waves -> full occupancy; next-row prefetch for ILP.
// Atomics only for chunk-straddling segments; pooled pre-zeroed by memset.
// ---------------------------------------------------------------------------
__global__ __launch_bounds__(256)
void k_pool2(const float* __restrict__ hidden, const int* __restrict__ nseg,
             const int* __restrict__ bpos, const int* __restrict__ segid,
             float* __restrict__ pooled, int S) {
    const int wave = threadIdx.x >> 6;
    const int lane = threadIdx.x & 63;
    const int g  = blockIdx.x * 4 + wave;      // 0 .. B*(LL/CH)*2 - 1
    const int hf = g & 1;
    const int cg = g >> 1;                     // 0 .. B*(LL/CH)-1
    const int b  = cg / (LL / CH);
    const int c  = cg % (LL / CH);
    const int t0 = c * CH;
    const int col = hf * 256 + lane * 4;
    const int n  = nseg[b];
    const int* sgid = segid + b * LL;
    const int* bp   = bpos + b * LL;
    const float* hb = hidden + (size_t)b * LL * DD + col;
    float* pb = pooled + (size_t)b * S * DD + col;

    float4 a = {0.f, 0.f, 0.f, 0.f};
    int cur = -1;
    int cur_start = 0;

    float4 vnext = *reinterpret_cast<const float4*>(&hb[(size_t)t0 * DD]);
#pragma unroll
    for (int t = t0; t < t0 + CH; t++) {
        float4 v = vnext;
        if (t + 1 < t0 + CH)
            vnext = *reinterpret_cast<const float4*>(&hb[(size_t)(t + 1) * DD]);
        int sg = sgid[t];
        if (sg != cur) {
            if (cur >= 0) {
                int real_end = (cur < n) ? bp[cur] : (LL - 1);
                float inv = 1.0f / (float)(real_end - cur_start + 1);
                float* dst = pb + (size_t)cur * DD;
                bool complete = (cur_start >= t0) && (t - 1 == real_end);
                if (complete) {
                    float4 r = {a.x * inv, a.y * inv, a.z * inv, a.w * inv};
                    *reinterpret_cast<float4*>(dst) = r;
                } else {
                    atomicAdd(dst + 0, a.x * inv);
                    atomicAdd(dst + 1, a.y * inv);
                    atomicAdd(dst + 2, a.z * inv);
                    atomicAdd(dst + 3, a.w * inv);
                }
            }
            if (sg < S) {
                cur = sg;
                cur_start = (sg > 0) ? bp[sg - 1] + 1 : 0;
                a = {0.f, 0.f, 0.f, 0.f};
            } else {
                cur = -1;
            }
        }
        if (cur >= 0) { a.x += v.x; a.y += v.y; a.z += v.z; a.w += v.w; }
    }
    if (cur >= 0) {
        int real_end = (cur < n) ? bp[cur] : (LL - 1);
        float inv = 1.0f / (float)(real_end - cur_start + 1);
        float* dst = pb + (size_t)cur * DD;
        bool complete = (cur_start >= t0) && (t0 + CH - 1 == real_end);
        if (complete) {
            float4 r = {a.x * inv, a.y * inv, a.z * inv, a.w * inv};
            *reinterpret_cast<float4*>(dst) = r;
        } else {
            atomicAdd(dst + 0, a.x * inv);
            atomicAdd(dst + 1, a.y * inv);
            atomicAdd(dst + 2, a.z * inv);
            atomicAdd(dst + 3, a.w * inv);
        }
    }
}

// ---------------------------------------------------------------------------
extern "C" void kernel_launch(void* const* d_in, const int* in_sizes, int n_in,
                              void* d_out, int out_size, void* d_ws, size_t ws_size,
                              hipStream_t stream) {
    const float* hidden  = (const float*)d_in[0];
    const float* lengths = (const float*)d_in[1];
    const float* W1      = (const float*)d_in[2];
    const float* b1      = (const float*)d_in[3];
    const float* W2      = (const float*)d_in[4];
    const float* b2      = (const float*)d_in[5];
    float* out           = (float*)d_out;

    const int S = (out_size - BB * LL - 2 * BB) / (BB * DD);

    float* logits = (float*)d_ws;                                     // B*L f32
    int*   bpos   = (int*)((char*)d_ws + (size_t)BB * LL * 4);        // B*L i32
    int*   segid  = (int*)((char*)d_ws + (size_t)2 * BB * LL * 4);    // B*L i32
    int*   nseg   = (int*)((char*)d_ws + (size_t)3 * BB * LL * 4);    // B i32
    unsigned short* wt_hi = (unsigned short*)((char*)d_ws + (size_t)3 * BB * LL * 4 + 1024);
    unsigned short* wt_lo = wt_hi + (size_t)DD * DD;

    hipMemsetAsync(out, 0, (size_t)BB * S * DD * sizeof(float), stream);

    k_split<<<64, 256, 0, stream>>>(W1, wt_hi, wt_lo, logits);
    k_mfma<<<1024, 512, 0, stream>>>(hidden, wt_hi, wt_lo, b1, W2, logits);
    k_bound<<<BB, 1024, 0, stream>>>(logits, lengths, b2, out, S, nseg, bpos, segid);
    k_pool2<<<(BB * (LL / CH) * 2) / 4, 256, 0, stream>>>(hidden, nseg, bpos, segid, out, S);
}